// Round 8
// baseline (419.688 us; speedup 1.0000x reference)
//
#include <hip/hip_runtime.h>

#define EPS_BN 1e-5f

typedef __attribute__((ext_vector_type(8))) short short8;   // 8 bf16 (4 VGPR)
typedef __attribute__((ext_vector_type(4))) float floatx4;  // MFMA C/D, nt-store

__device__ __forceinline__ short f2bf(float f) {            // RNE f32->bf16
    unsigned u = __float_as_uint(f);
    u += 0x7FFF + ((u >> 16) & 1);
    return (short)(u >> 16);
}
__device__ __forceinline__ float bf2f(short s) {
    return __uint_as_float(((unsigned)(unsigned short)s) << 16);
}

// ===========================================================================
// R10: persistent-block gather (the one positive-evidence lever left).
//  - 1024 blocks (4/CU, 32 waves/CU), grid-stride over 128-output tiles.
//    Eliminates 4190 block launch/drain cold-starts (R5 measured occ 81%
//    persistent vs 76% per-tile; R5's slowdown was clamp-loads, not this).
//  - Per tile: {stage W from L2-hot packedW; bar; R7b-EXACT guarded j-loop;
//    bar; repack y->bf16 into sW (dead W) + reg stats; bar; coalesced
//    stream; bar}. LDS stays 33 KB -> 4 blocks/CU.
//  - BN stats in registers across tiles, one reduce per block (R5 pattern).
// R5 lesson: NEVER broadcast-clamp loads. R6: launch_bounds(512,8) only.
// R8: no manual j-pipelining. R9: write volume is free; reads are the wall.
//
// ws layout (bytes):
//   [512, 1024)   a[64], b[64] (finalize out)
//   [1024, +32K)  packedW: [j][tile][lane][8] bf16
//   then          partials: [128][nbg] f32
//   then          slot: num_out*8 int   \ one 0xFF memset
//   then          cm_inv: num_out u32   /  (contiguous)
//   then          next: n_vox int
//   then          y_bf16: num_out*64 bf16 (bf16 path only, ws-size checked)
// ===========================================================================

// Fused scatter + W-pack. Blocks 0-7 additionally pack W into fragment order:
// packed[((j*4+t)*64+l)*8+i] = bf16(W[j][(l>>4)*8+i][(l&15)+16t])
__global__ void scatter_pack(const int* __restrict__ out_idx,
                             const int* __restrict__ k_idx,
                             const float* __restrict__ W,
                             int* __restrict__ slot, int* __restrict__ next,
                             unsigned* __restrict__ cm_inv,
                             short* __restrict__ packed, int n)
{
    const int i = blockIdx.x * 256 + threadIdx.x;
    if (blockIdx.x < 8) {                       // W pack (2048 threads)
        const int s = i;
        const int j = s >> 8, t = (s >> 6) & 3, l = s & 63;
        const int k0 = (l >> 4) * 8, c = (l & 15) + 16 * t;
        short8 v;
#pragma unroll
        for (int q = 0; q < 8; ++q)
            v[q] = f2bf(W[(j * 32 + k0 + q) * 64 + c]);
        ((short8*)packed)[s] = v;
    }
    if (i < n) {
        const int o = out_idx[i];
        const int k = k_idx[i];
        int old = atomicExch(&slot[(size_t)o * 8 + k], i);
        next[i] = old;                          // chain walk needs -1 terminator
        if (old >= 0) atomicAnd(&cm_inv[o], ~(1u << k));   // rare (~2%)
    }
}

// ---------------------------------------------------------------------------
// Persistent MFMA gather: 8 waves x 16 outputs = 128 outputs per tile.
// YB16: y stored bf16 via LDS repack (sW reused per tile); else f32 direct.
// ---------------------------------------------------------------------------
template <bool YB16>
__global__ __launch_bounds__(512, 8) void gather_mfma(
    const float* __restrict__ x, const short* __restrict__ packedW,
    const int* __restrict__ slot, const int* __restrict__ next_arr,
    const unsigned* __restrict__ cm_inv,
    float* __restrict__ out, short* __restrict__ yb,
    float* __restrict__ partials, int num_out, int ntiles)
{
    __shared__ short sW[16384];          // 32 KB: W fragments; reused as y tile
    __shared__ float s_stat[128];

    const int tid = threadIdx.x;
    const int wave = tid >> 6, lane = tid & 63;
    const int quad = lane >> 4, row = lane & 15;
    const short8* bw = (const short8*)sW;

    if (tid < 128) s_stat[tid] = 0.f;

    float statS[4] = {0.f, 0.f, 0.f, 0.f};
    float statQ[4] = {0.f, 0.f, 0.f, 0.f};

    for (int tile = blockIdx.x; tile < ntiles; tile += gridDim.x) {
        const int obase = tile * 128 + wave * 16;
        const int o = obase + row;
        const bool valid_o = (o < num_out);

        // slot + chainmask loads issued first: latency hides under W staging.
        int4 sl0 = make_int4(-1, -1, -1, -1), sl1 = sl0;
        unsigned cmraw = 0xFFFFFFFFu;    // inverted: bit==0 means chain present
        if (valid_o) {
            const int4* sp = (const int4*)(slot + (size_t)o * 8);
            sl0 = sp[0]; sl1 = sp[1];
            cmraw = cm_inv[o];
        }

        // Stage W (L2-hot after first pass; copy ~0.25us, launch churn was
        // the real cost of per-tile blocks).
        for (int i = tid; i < 2048; i += 512)
            ((short8*)sW)[i] = ((const short8*)packedW)[i];
        __syncthreads();

        const unsigned cm = ~cmraw;      // bit j set => duplicate chain at j

        floatx4 acc[4] = {{0,0,0,0},{0,0,0,0},{0,0,0,0},{0,0,0,0}};

#pragma unroll
        for (int j = 0; j < 8; ++j) {
            const int v = (j < 4) ? ((j == 0) ? sl0.x : (j == 1) ? sl0.y : (j == 2) ? sl0.z : sl0.w)
                                  : ((j == 4) ? sl1.x : (j == 5) ? sl1.y : (j == 6) ? sl1.z : sl1.w);
            if (!__any(v >= 0)) continue;        // whole wave empty at this j
            float4 xa = make_float4(0.f, 0.f, 0.f, 0.f), xb = xa;
            if (v >= 0) {                        // exec-masked (empty lanes free)
                const float4* xp = (const float4*)(x + (size_t)v * 32) + quad * 2;
                xa = xp[0]; xb = xp[1];
            }
            if (__builtin_expect(__any((cm >> j) & 1u), 0)) {   // rare dup chain
                int w = (v >= 0 && ((cm >> j) & 1u)) ? next_arr[v] : -1;
                while (__any(w >= 0)) {
                    if (w >= 0) {
                        const float4* xp2 = (const float4*)(x + (size_t)w * 32) + quad * 2;
                        float4 ya = xp2[0], yb4 = xp2[1];
                        xa.x += ya.x; xa.y += ya.y; xa.z += ya.z; xa.w += ya.w;
                        xb.x += yb4.x; xb.y += yb4.y; xb.z += yb4.z; xb.w += yb4.w;
                        w = next_arr[w];
                    }
                }
            }
            short8 afrag;
            afrag[0] = f2bf(xa.x); afrag[1] = f2bf(xa.y);
            afrag[2] = f2bf(xa.z); afrag[3] = f2bf(xa.w);
            afrag[4] = f2bf(xb.x); afrag[5] = f2bf(xb.y);
            afrag[6] = f2bf(xb.z); afrag[7] = f2bf(xb.w);

            const int jb = j * 256;
#pragma unroll
            for (int t = 0; t < 4; ++t) {
                const short8 bfrag = bw[jb + t * 64 + lane];
                acc[t] = __builtin_amdgcn_mfma_f32_16x16x32_bf16(afrag, bfrag, acc[t], 0, 0, 0);
            }
        }

        // Epilogue: C layout col=lane&15, row=quad*4+reg.
        if constexpr (YB16) {
            __syncthreads();             // all waves done reading sW (W)
            short* ylds = sW;            // reuse: [wave][16 rows][64 ch] bf16
#pragma unroll
            for (int t = 0; t < 4; ++t) {
#pragma unroll
                for (int r = 0; r < 4; ++r) {
                    const int rl = quad * 4 + r;
                    const int c = (lane & 15) + 16 * t;
                    const float val = acc[t][r];
                    ylds[wave * 1024 + rl * 64 + c] = f2bf(val);
                    if (obase + rl < num_out) {
                        statS[t] += val; statQ[t] += val * val;
                    }
                }
            }
            __syncthreads();             // ylds complete
            // Stream 128 rows x 128 B = 1024 short8, coalesced.
            const size_t rbase = (size_t)tile * 128;
#pragma unroll
            for (int k = 0; k < 2; ++k) {
                const int i = tid + k * 512;
                if (rbase + (i >> 3) < (size_t)num_out)
                    ((short8*)yb)[rbase * 8 + i] = ((const short8*)ylds)[i];
            }
            __syncthreads();             // stream reads done before next stage
        } else {
#pragma unroll
            for (int t = 0; t < 4; ++t) {
                const int c = (lane & 15) + 16 * t;
#pragma unroll
                for (int r = 0; r < 4; ++r) {
                    const int oc = obase + quad * 4 + r;
                    const float val = acc[t][r];
                    if (oc < num_out) {
                        out[(size_t)oc * 64 + c] = val;
                        statS[t] += val; statQ[t] += val * val;
                    }
                }
            }
            __syncthreads();             // done reading sW before next stage
        }
    }

    // Final stats reduce (once per block)
#pragma unroll
    for (int t = 0; t < 4; ++t) {
        float sum = statS[t], sq = statQ[t];
        sum += __shfl_xor(sum, 16, 64); sum += __shfl_xor(sum, 32, 64);
        sq  += __shfl_xor(sq, 16, 64);  sq  += __shfl_xor(sq, 32, 64);
        if (quad == 0) {
            const int c = (lane & 15) + 16 * t;
            atomicAdd(&s_stat[c], sum);
            atomicAdd(&s_stat[64 + c], sq);
        }
    }
    __syncthreads();
    if (tid < 128) partials[(size_t)tid * gridDim.x + blockIdx.x] = s_stat[tid];
}

// One block per channel c: reduce partials, emit a[c], b[c].
// (conv bias cancels under BN: final = (acc-mean)*rsqrt(var)*gamma+beta)
__global__ __launch_bounds__(256) void reduce_finalize(
    const float* __restrict__ partials, const float* __restrict__ gamma,
    const float* __restrict__ beta, float* __restrict__ ws_ab,
    int nb, float inv_n)
{
    __shared__ float r1[256], r2[256];
    const int c = blockIdx.x, t = threadIdx.x;
    float s1 = 0.f, s2 = 0.f;
    for (int i = t; i < nb; i += 256) {
        s1 += partials[(size_t)c * nb + i];
        s2 += partials[(size_t)(c + 64) * nb + i];
    }
    r1[t] = s1; r2[t] = s2;
    __syncthreads();
    for (int d = 128; d > 0; d >>= 1) {
        if (t < d) { r1[t] += r1[t + d]; r2[t] += r2[t + d]; }
        __syncthreads();
    }
    if (t == 0) {
        const float mean = r1[0] * inv_n;
        const float var = r2[0] * inv_n - mean * mean;
        const float a = gamma[c] * rsqrtf(var + EPS_BN);
        ws_ab[c] = a;                        // a[64]
        ws_ab[64 + c] = beta[c] - mean * a;  // b[64]
    }
}

// bf16 apply: thread handles 8 channels (group g = tid&7) of one row per iter.
__global__ __launch_bounds__(256) void apply_bf16(
    const short* __restrict__ yb, float* __restrict__ out,
    const float* __restrict__ ws_ab, int ngroups)   // ngroups = num_out*8
{
    const int tid = blockIdx.x * 256 + threadIdx.x;
    const int stride = gridDim.x * 256;              // multiple of 8
    const int g = tid & 7;
    float a[8], b[8];
#pragma unroll
    for (int q = 0; q < 8; ++q) {
        a[q] = ws_ab[g * 8 + q];
        b[q] = ws_ab[64 + g * 8 + q];
    }
    const short8* y8 = (const short8*)yb;
    floatx4* o4 = (floatx4*)out;
    for (int i = tid; i < ngroups; i += stride) {
        const short8 v = y8[i];
        floatx4 o0, o1;
        o0.x = fmaxf(fmaf(bf2f(v[0]), a[0], b[0]), 0.f);
        o0.y = fmaxf(fmaf(bf2f(v[1]), a[1], b[1]), 0.f);
        o0.z = fmaxf(fmaf(bf2f(v[2]), a[2], b[2]), 0.f);
        o0.w = fmaxf(fmaf(bf2f(v[3]), a[3], b[3]), 0.f);
        o1.x = fmaxf(fmaf(bf2f(v[4]), a[4], b[4]), 0.f);
        o1.y = fmaxf(fmaf(bf2f(v[5]), a[5], b[5]), 0.f);
        o1.z = fmaxf(fmaf(bf2f(v[6]), a[6], b[6]), 0.f);
        o1.w = fmaxf(fmaf(bf2f(v[7]), a[7], b[7]), 0.f);
        __builtin_nontemporal_store(o0, o4 + (size_t)i * 2);
        __builtin_nontemporal_store(o1, o4 + (size_t)i * 2 + 1);
    }
}

// f32 fallback apply (out holds f32 y in-place).
__global__ __launch_bounds__(256) void apply_f32(
    float* __restrict__ out, const float* __restrict__ ws_ab, int n4)
{
    const int tid = blockIdx.x * 256 + threadIdx.x;
    const int stride = gridDim.x * 256;
    const int cg = tid & 15;
    const floatx4 a = ((const floatx4*)ws_ab)[cg];
    const floatx4 b = ((const floatx4*)(ws_ab + 64))[cg];
    floatx4* o4 = (floatx4*)out;
    for (int i = tid; i < n4; i += stride) {
        floatx4 v = o4[i];
        v.x = fmaxf(fmaf(v.x, a.x, b.x), 0.f);
        v.y = fmaxf(fmaf(v.y, a.y, b.y), 0.f);
        v.z = fmaxf(fmaf(v.z, a.z, b.z), 0.f);
        v.w = fmaxf(fmaf(v.w, a.w, b.w), 0.f);
        __builtin_nontemporal_store(v, o4 + i);
    }
}

extern "C" void kernel_launch(void* const* d_in, const int* in_sizes, int n_in,
                              void* d_out, int out_size, void* d_ws, size_t ws_size,
                              hipStream_t stream)
{
    const float* x     = (const float*)d_in[0];
    const float* W     = (const float*)d_in[1];
    // d_in[2] = bias: cancels under BN, unused.
    const float* gamma = (const float*)d_in[3];
    const float* beta  = (const float*)d_in[4];
    const int* k_idx   = (const int*)d_in[5];
    const int* out_idx = (const int*)d_in[6];

    const int n_vox   = in_sizes[5];
    const int num_out = out_size / 64;
    const int ntiles  = (num_out + 127) / 128;   // 128 outputs per tile
    const int nbg     = (ntiles < 1024) ? ntiles : 1024;   // persistent blocks
    float* out = (float*)d_out;

    char* p = (char*)d_ws;
    float* ws_ab    = (float*)(p + 512);                 // a[64], b[64]
    short* packedW  = (short*)(p + 1024);                // 32 KB
    float* partials = (float*)(p + 1024 + 32768);        // 128*nbg f32
    size_t off      = 1024 + 32768 + (size_t)128 * nbg * 4;
    int*   slot     = (int*)(p + off);                   // num_out*8
    unsigned* cm_inv = (unsigned*)(slot + (size_t)num_out * 8);  // num_out
    int*   next     = (int*)(cm_inv + num_out);          // n_vox
    size_t ybOff    = (off + (size_t)num_out * 36 + (size_t)n_vox * 4 + 15) & ~(size_t)15;
    short* yb       = (short*)(p + ybOff);               // num_out*64 bf16
    const bool useBf16 = (ws_size >= ybOff + (size_t)num_out * 128);

    // ONE memset: slot (=-1) and cm_inv (=0xFFFFFFFF, inverted chainmask)
    (void)hipMemsetAsync(slot, 0xFF, (size_t)num_out * 9 * sizeof(int), stream);

    const int nsb = (n_vox + 255) / 256;                 // >= 8 always here
    scatter_pack  <<<nsb, 256, 0, stream>>>(out_idx, k_idx, W, slot, next, cm_inv, packedW, n_vox);
    if (useBf16) {
        gather_mfma<true><<<nbg, 512, 0, stream>>>(x, packedW, slot, next, cm_inv, out, yb, partials, num_out, ntiles);
        reduce_finalize<<<64, 256, 0, stream>>>(partials, gamma, beta, ws_ab, nbg, 1.0f / (float)num_out);
        apply_bf16 <<<4096, 256, 0, stream>>>(yb, out, ws_ab, num_out * 8);
    } else {
        gather_mfma<false><<<nbg, 512, 0, stream>>>(x, packedW, slot, next, cm_inv, out, yb, partials, num_out, ntiles);
        reduce_finalize<<<64, 256, 0, stream>>>(partials, gamma, beta, ws_ab, nbg, 1.0f / (float)num_out);
        apply_f32  <<<4096, 256, 0, stream>>>(out, ws_ab, out_size / 4);
    }
}

// Round 10
// 401.771 us; speedup vs baseline: 1.0446x; 1.0446x over previous
//
#include <hip/hip_runtime.h>

#define EPS_BN 1e-5f

typedef __attribute__((ext_vector_type(8))) short short8;   // 8 bf16 (4 VGPR)
typedef __attribute__((ext_vector_type(4))) short sbf4;     // 4 bf16 (8 B)
typedef __attribute__((ext_vector_type(4))) float floatx4;  // MFMA C/D, nt-store

__device__ __forceinline__ short f2bf(float f) {            // RNE f32->bf16
    unsigned u = __float_as_uint(f);
    u += 0x7FFF + ((u >> 16) & 1);
    return (short)(u >> 16);
}
__device__ __forceinline__ float bf2f(short s) {
    return __uint_as_float(((unsigned)(unsigned short)s) << 16);
}

// ===========================================================================
// R11b: bf16-x (R11 with short4->sbf4 rename; HIP predefines short4).
// x is pre-converted to bf16 once (streaming, fused into scatter_pack), so
// the gather j-body is ONE 16B load straight into the A-fragment: half the
// random-read bytes/requests, zero VALU between load and MFMA. Gather/apply
// otherwise R7b-exact (best measured total 404.6; six scheduling variants
// all >= 122us on gather -- this attacks payload). Dup chains (rare)
// accumulate f32 and re-round.
// Ledger: R5 never clamp-loads | R6 launch_bounds(512,8) only | R8 no manual
// pipelining | R9 write volume free | R10 no persistent/per-tile re-stage.
//
// ws layout (bytes):
//   [512, 1024)   a[64], b[64] (finalize out)
//   [1024, +32K)  packedW: [j][tile][lane][8] bf16
//   then          partials: [128][nb] f32
//   then          slot: num_out*8 int   \ one 0xFF memset
//   then          cm_inv: num_out u32   /  (contiguous)
//   then          next: n_vox int
//   then          xb: n_vox*32 bf16 (bf16-x path only, ws-size checked)
// ===========================================================================

// Fused scatter + W-pack + x->bf16 conversion.
// packed[((j*4+t)*64+l)*8+i] = bf16(W[j][(l>>4)*8+i][(l&15)+16t])
__global__ void scatter_pack(const int* __restrict__ out_idx,
                             const int* __restrict__ k_idx,
                             const float* __restrict__ W,
                             const float* __restrict__ x,
                             int* __restrict__ slot, int* __restrict__ next,
                             unsigned* __restrict__ cm_inv,
                             short* __restrict__ packed,
                             short* __restrict__ xb,   // may be null (no convert)
                             int n)
{
    const int i = blockIdx.x * 256 + threadIdx.x;
    if (blockIdx.x < 8) {                       // W pack (2048 threads)
        const int s = i;
        const int j = s >> 8, t = (s >> 6) & 3, l = s & 63;
        const int k0 = (l >> 4) * 8, c = (l & 15) + 16 * t;
        short8 v;
#pragma unroll
        for (int q = 0; q < 8; ++q)
            v[q] = f2bf(W[(j * 32 + k0 + q) * 64 + c]);
        ((short8*)packed)[s] = v;
    }
    if (i < n) {
        const int o = out_idx[i];
        const int k = k_idx[i];
        int old = atomicExch(&slot[(size_t)o * 8 + k], i);
        next[i] = old;                          // chain walk needs -1 terminator
        if (old >= 0) atomicAnd(&cm_inv[o], ~(1u << k));   // rare (~2%)
    }
    if (xb) {                                   // x -> bf16, flat grid-stride
        const int nf4 = n * 8;                  // n*32 floats / 4
        const int stride = gridDim.x * 256;
        for (int idx = i; idx < nf4; idx += stride) {
            const float4 v = ((const float4*)x)[idx];
            sbf4 s;
            s.x = f2bf(v.x); s.y = f2bf(v.y);
            s.z = f2bf(v.z); s.w = f2bf(v.w);
            ((sbf4*)xb)[idx] = s;
        }
    }
}

// ---------------------------------------------------------------------------
// MFMA gather: block = 8 waves x 16 outputs = 128 outputs. R7b structure.
// XB16: A-fragments loaded directly from bf16 x (one dwordx4 per lane per j).
// ---------------------------------------------------------------------------
template <bool XB16>
__global__ __launch_bounds__(512, 8) void gather_mfma(
    const float* __restrict__ x, const short* __restrict__ xb,
    const short* __restrict__ packedW,
    const int* __restrict__ slot, const int* __restrict__ next_arr,
    const unsigned* __restrict__ cm_inv,
    float* __restrict__ out, float* __restrict__ partials,
    int num_out, int nb)
{
    __shared__ short sW[16384];          // 32 KB: [j][tile][lane][8]
    __shared__ float s_stat[128];

    const int tid = threadIdx.x;
    const int wave = tid >> 6, lane = tid & 63;
    const int quad = lane >> 4, row = lane & 15;
    const int obase = blockIdx.x * 128 + wave * 16;
    const int o = obase + row;
    const bool valid_o = (o < num_out);

    // Hoisted slot + chainmask loads: latency hides under W staging + barrier.
    int4 sl0 = make_int4(-1, -1, -1, -1), sl1 = sl0;
    unsigned cmraw = 0xFFFFFFFFu;        // inverted: bit==0 means chain present
    if (valid_o) {
        const int4* sp = (const int4*)(slot + (size_t)o * 8);
        sl0 = sp[0]; sl1 = sp[1];
        cmraw = cm_inv[o];
    }

    if (tid < 128) s_stat[tid] = 0.f;
    for (int i = tid; i < 2048; i += 512)
        ((short8*)sW)[i] = ((const short8*)packedW)[i];
    __syncthreads();

    const unsigned cm = ~cmraw;          // bit j set => duplicate chain at j

    floatx4 acc[4] = {{0,0,0,0},{0,0,0,0},{0,0,0,0},{0,0,0,0}};
    const short8* bw = (const short8*)sW;

#pragma unroll
    for (int j = 0; j < 8; ++j) {
        const int v = (j < 4) ? ((j == 0) ? sl0.x : (j == 1) ? sl0.y : (j == 2) ? sl0.z : sl0.w)
                              : ((j == 4) ? sl1.x : (j == 5) ? sl1.y : (j == 6) ? sl1.z : sl1.w);
        if (!__any(v >= 0)) continue;            // whole wave empty at this j
        short8 afrag = {0, 0, 0, 0, 0, 0, 0, 0};
        if constexpr (XB16) {
            if (v >= 0)                          // exec-masked, 16B -> fragment
                afrag = ((const short8*)(xb + (size_t)v * 32))[quad];
            if (__builtin_expect(__any((cm >> j) & 1u), 0)) {   // rare dup chain
                float a8[8];
#pragma unroll
                for (int q = 0; q < 8; ++q) a8[q] = bf2f(afrag[q]);
                int w = (v >= 0 && ((cm >> j) & 1u)) ? next_arr[v] : -1;
                while (__any(w >= 0)) {
                    if (w >= 0) {
                        const short8 yv = ((const short8*)(xb + (size_t)w * 32))[quad];
#pragma unroll
                        for (int q = 0; q < 8; ++q) a8[q] += bf2f(yv[q]);
                        w = next_arr[w];
                    }
                }
#pragma unroll
                for (int q = 0; q < 8; ++q) afrag[q] = f2bf(a8[q]);
            }
        } else {
            float4 xa = make_float4(0.f, 0.f, 0.f, 0.f), xbv = xa;
            if (v >= 0) {                        // exec-masked (empty lanes free)
                const float4* xp = (const float4*)(x + (size_t)v * 32) + quad * 2;
                xa = xp[0]; xbv = xp[1];
            }
            if (__builtin_expect(__any((cm >> j) & 1u), 0)) {   // rare dup chain
                int w = (v >= 0 && ((cm >> j) & 1u)) ? next_arr[v] : -1;
                while (__any(w >= 0)) {
                    if (w >= 0) {
                        const float4* xp2 = (const float4*)(x + (size_t)w * 32) + quad * 2;
                        float4 ya = xp2[0], yb4 = xp2[1];
                        xa.x += ya.x; xa.y += ya.y; xa.z += ya.z; xa.w += ya.w;
                        xbv.x += yb4.x; xbv.y += yb4.y; xbv.z += yb4.z; xbv.w += yb4.w;
                        w = next_arr[w];
                    }
                }
            }
            afrag[0] = f2bf(xa.x); afrag[1] = f2bf(xa.y);
            afrag[2] = f2bf(xa.z); afrag[3] = f2bf(xa.w);
            afrag[4] = f2bf(xbv.x); afrag[5] = f2bf(xbv.y);
            afrag[6] = f2bf(xbv.z); afrag[7] = f2bf(xbv.w);
        }

        const int jb = j * 256;
#pragma unroll
        for (int t = 0; t < 4; ++t) {
            const short8 bfrag = bw[jb + t * 64 + lane];
            acc[t] = __builtin_amdgcn_mfma_f32_16x16x32_bf16(afrag, bfrag, acc[t], 0, 0, 0);
        }
    }

    // Epilogue: C layout col=lane&15, row=quad*4+reg. Store + fused stats.
#pragma unroll
    for (int t = 0; t < 4; ++t) {
        const int c = (lane & 15) + 16 * t;
        float sum = 0.f, sq = 0.f;
#pragma unroll
        for (int r = 0; r < 4; ++r) {
            const int oc = obase + quad * 4 + r;
            const float val = acc[t][r];
            if (oc < num_out) {
                out[(size_t)oc * 64 + c] = val;
                sum += val; sq += val * val;
            }
        }
        sum += __shfl_xor(sum, 16, 64); sum += __shfl_xor(sum, 32, 64);
        sq  += __shfl_xor(sq, 16, 64);  sq  += __shfl_xor(sq, 32, 64);
        if (quad == 0) {
            atomicAdd(&s_stat[c], sum);
            atomicAdd(&s_stat[64 + c], sq);
        }
    }
    __syncthreads();
    if (tid < 128) partials[(size_t)tid * nb + blockIdx.x] = s_stat[tid];
}

// One block per channel c: reduce partials, emit a[c], b[c].
// (conv bias cancels under BN: final = (acc-mean)*rsqrt(var)*gamma+beta)
__global__ __launch_bounds__(256) void reduce_finalize(
    const float* __restrict__ partials, const float* __restrict__ gamma,
    const float* __restrict__ beta, float* __restrict__ ws_ab,
    int nb, float inv_n)
{
    __shared__ float r1[256], r2[256];
    const int c = blockIdx.x, t = threadIdx.x;
    float s1 = 0.f, s2 = 0.f;
    for (int i = t; i < nb; i += 256) {
        s1 += partials[(size_t)c * nb + i];
        s2 += partials[(size_t)(c + 64) * nb + i];
    }
    r1[t] = s1; r2[t] = s2;
    __syncthreads();
    for (int d = 128; d > 0; d >>= 1) {
        if (t < d) { r1[t] += r1[t + d]; r2[t] += r2[t + d]; }
        __syncthreads();
    }
    if (t == 0) {
        const float mean = r1[0] * inv_n;
        const float var = r2[0] * inv_n - mean * mean;
        const float a = gamma[c] * rsqrtf(var + EPS_BN);
        ws_ab[c] = a;                        // a[64]
        ws_ab[64 + c] = beta[c] - mean * a;  // b[64]
    }
}

__global__ __launch_bounds__(256) void apply_kernel(
    float* __restrict__ out, const float* __restrict__ ws_ab, int n4)
{
    const int tid = blockIdx.x * 256 + threadIdx.x;
    const int stride = gridDim.x * 256;          // multiple of 16 -> cg fixed
    const int cg = tid & 15;
    const floatx4 a = ((const floatx4*)ws_ab)[cg];
    const floatx4 b = ((const floatx4*)(ws_ab + 64))[cg];
    floatx4* o4 = (floatx4*)out;
    for (int i = tid; i < n4; i += stride) {
        floatx4 v = o4[i];                       // regular load: y is L3-hot
        v.x = fmaxf(fmaf(v.x, a.x, b.x), 0.f);
        v.y = fmaxf(fmaf(v.y, a.y, b.y), 0.f);
        v.z = fmaxf(fmaf(v.z, a.z, b.z), 0.f);
        v.w = fmaxf(fmaf(v.w, a.w, b.w), 0.f);
        __builtin_nontemporal_store(v, o4 + i);  // out never re-read
    }
}

extern "C" void kernel_launch(void* const* d_in, const int* in_sizes, int n_in,
                              void* d_out, int out_size, void* d_ws, size_t ws_size,
                              hipStream_t stream)
{
    const float* x     = (const float*)d_in[0];
    const float* W     = (const float*)d_in[1];
    // d_in[2] = bias: cancels under BN, unused.
    const float* gamma = (const float*)d_in[3];
    const float* beta  = (const float*)d_in[4];
    const int* k_idx   = (const int*)d_in[5];
    const int* out_idx = (const int*)d_in[6];

    const int n_vox   = in_sizes[5];
    const int num_out = out_size / 64;
    const int nb      = (num_out + 127) / 128;   // gather blocks (128 outputs)
    float* out = (float*)d_out;

    char* p = (char*)d_ws;
    float* ws_ab    = (float*)(p + 512);                 // a[64], b[64]
    short* packedW  = (short*)(p + 1024);                // 32 KB
    float* partials = (float*)(p + 1024 + 32768);        // 128*nb f32
    size_t off      = 1024 + 32768 + (size_t)128 * nb * 4;
    int*   slot     = (int*)(p + off);                   // num_out*8
    unsigned* cm_inv = (unsigned*)(slot + (size_t)num_out * 8);  // num_out
    int*   next     = (int*)(cm_inv + num_out);          // n_vox
    size_t xbOff    = (off + (size_t)num_out * 36 + (size_t)n_vox * 4 + 15) & ~(size_t)15;
    short* xb       = (short*)(p + xbOff);               // n_vox*32 bf16
    const bool useXb = (ws_size >= xbOff + (size_t)n_vox * 64);

    // ONE memset: slot (=-1) and cm_inv (=0xFFFFFFFF, inverted chainmask)
    (void)hipMemsetAsync(slot, 0xFF, (size_t)num_out * 9 * sizeof(int), stream);

    const int nsb = (n_vox + 255) / 256;                 // >= 8 always here
    scatter_pack  <<<nsb, 256, 0, stream>>>(out_idx, k_idx, W, x, slot, next,
                                            cm_inv, packedW, useXb ? xb : nullptr, n_vox);
    if (useXb) {
        gather_mfma<true><<<nb, 512, 0, stream>>>(x, xb, packedW, slot, next, cm_inv,
                                                  out, partials, num_out, nb);
    } else {
        gather_mfma<false><<<nb, 512, 0, stream>>>(x, xb, packedW, slot, next, cm_inv,
                                                   out, partials, num_out, nb);
    }
    reduce_finalize<<<64, 256, 0, stream>>>(partials, gamma, beta, ws_ab, nb, 1.0f / (float)num_out);
    apply_kernel  <<<4096, 256, 0, stream>>>(out, ws_ab, out_size / 4);
}